// Round 1
// baseline (424.351 us; speedup 1.0000x reference)
//
#include <hip/hip_runtime.h>
#include <math.h>

typedef unsigned int u32;

// ---------------------------------------------------------------------------
// Exact 0.99-quantile of |x| via 2-level radix select on float bit patterns,
// then affine fake-quantize. All selection is bit-exact vs np.sort.
// ws layout: [0..2047] u32 level-1 histogram; [2048..2055] scalars
//   sc[0] = selected top-11-bit bin (B1), sc[1] = residual rank,
//   sc[2] = scale (float bits)
// Level-2 histogram (1M u32 = 4 MB) lives in d_out (overwritten afterwards).
// ---------------------------------------------------------------------------

__global__ __launch_bounds__(1024) void hist_top(const u32* __restrict__ x,
                                                 u32* __restrict__ g1,
                                                 long long n) {
  __shared__ u32 h[2048];
  const int t = threadIdx.x;
  for (int i = t; i < 2048; i += 1024) h[i] = 0;
  __syncthreads();

  const long long n4 = n >> 2;
  const long long stride = (long long)gridDim.x * 1024;
  const uint4* x4 = (const uint4*)x;
  for (long long i = (long long)blockIdx.x * 1024 + t; i < n4; i += stride) {
    uint4 v = x4[i];
    atomicAdd(&h[(v.x & 0x7fffffffu) >> 20], 1u);
    atomicAdd(&h[(v.y & 0x7fffffffu) >> 20], 1u);
    atomicAdd(&h[(v.z & 0x7fffffffu) >> 20], 1u);
    atomicAdd(&h[(v.w & 0x7fffffffu) >> 20], 1u);
  }
  // generic tail (empty for this problem's n % 4 == 0)
  for (long long i = (n4 << 2) + (long long)blockIdx.x * 1024 + t; i < n;
       i += stride) {
    atomicAdd(&h[(x[i] & 0x7fffffffu) >> 20], 1u);
  }
  __syncthreads();
  for (int i = t; i < 2048; i += 1024) {
    u32 c = h[i];
    if (c) atomicAdd(&g1[i], c);
  }
}

__global__ __launch_bounds__(1024) void scan_top(const u32* __restrict__ g1,
                                                 u32* __restrict__ sc,
                                                 long long k_in) {
  __shared__ u32 s[1024];
  const int t = threadIdx.x;
  uint2 c2 = ((const uint2*)g1)[t];
  const u32 sum = c2.x + c2.y;
  s[t] = sum;
  __syncthreads();
  for (int off = 1; off < 1024; off <<= 1) {
    u32 add = (t >= off) ? s[t - off] : 0u;
    __syncthreads();
    s[t] += add;
    __syncthreads();
  }
  u32 ex = s[t] - sum;  // exclusive prefix of this thread's 2 bins
  const u32 k = (u32)k_in;
  u32 cnt[2] = {c2.x, c2.y};
  for (int i = 0; i < 2; ++i) {
    if (k >= ex && k < ex + cnt[i]) {
      sc[0] = (u32)(t * 2 + i);
      sc[1] = k - ex;
    }
    ex += cnt[i];
  }
}

__global__ __launch_bounds__(1024) void hist_low(const u32* __restrict__ x,
                                                 const u32* __restrict__ sc,
                                                 u32* __restrict__ g2,
                                                 long long n) {
  const u32 B1 = sc[0];
  const int t = threadIdx.x;
  const long long n4 = n >> 2;
  const long long stride = (long long)gridDim.x * 1024;
  const uint4* x4 = (const uint4*)x;
  for (long long i = (long long)blockIdx.x * 1024 + t; i < n4; i += stride) {
    uint4 v = x4[i];
    u32 a;
    a = v.x & 0x7fffffffu; if ((a >> 20) == B1) atomicAdd(&g2[a & 0xFFFFFu], 1u);
    a = v.y & 0x7fffffffu; if ((a >> 20) == B1) atomicAdd(&g2[a & 0xFFFFFu], 1u);
    a = v.z & 0x7fffffffu; if ((a >> 20) == B1) atomicAdd(&g2[a & 0xFFFFFu], 1u);
    a = v.w & 0x7fffffffu; if ((a >> 20) == B1) atomicAdd(&g2[a & 0xFFFFFu], 1u);
  }
  for (long long i = (n4 << 2) + (long long)blockIdx.x * 1024 + t; i < n;
       i += stride) {
    u32 a = x[i] & 0x7fffffffu;
    if ((a >> 20) == B1) atomicAdd(&g2[a & 0xFFFFFu], 1u);
  }
}

__global__ __launch_bounds__(1024) void scan_low(const u32* __restrict__ g2,
                                                 const float* __restrict__ gamma,
                                                 u32* __restrict__ sc) {
  __shared__ u32 s[1024];
  __shared__ u32 sChunk, sK2;
  const int t = threadIdx.x;
  const u32 B1 = sc[0];
  const u32 krem = sc[1];

  // Phase A: per-thread sum of 1024 contiguous bins (ordered chunks)
  const uint4* g4 = (const uint4*)(g2 + (size_t)t * 1024);
  u32 sum = 0;
#pragma unroll 8
  for (int i = 0; i < 256; ++i) {
    uint4 c = g4[i];
    sum += c.x + c.y + c.z + c.w;
  }
  s[t] = sum;
  __syncthreads();
  for (int off = 1; off < 1024; off <<= 1) {
    u32 add = (t >= off) ? s[t - off] : 0u;
    __syncthreads();
    s[t] += add;
    __syncthreads();
  }
  u32 ex = s[t] - sum;
  if (krem >= ex && krem < ex + sum) {
    sChunk = (u32)t;
    sK2 = krem - ex;
  }
  __syncthreads();
  const u32 c = sChunk;
  const u32 k2 = sK2;

  // Phase B: scan the 1024 bins of the selected chunk (coalesced)
  const u32 cnt = g2[(size_t)c * 1024 + t];
  __syncthreads();
  s[t] = cnt;
  __syncthreads();
  for (int off = 1; off < 1024; off <<= 1) {
    u32 add = (t >= off) ? s[t - off] : 0u;
    __syncthreads();
    s[t] += add;
    __syncthreads();
  }
  ex = s[t] - cnt;
  if (k2 >= ex && k2 < ex + cnt) {
    const u32 bits = (B1 << 20) | (c * 1024u + (u32)t);
    const float q = __uint_as_float(bits);
    float g = gamma[0];
    g = fminf(fmaxf(g, 0.1f), 10.0f);
    const float scale = (q / 127.0f) * g;
    ((float*)sc)[2] = scale;
  }
}

__global__ __launch_bounds__(256) void quantize(const float* __restrict__ x,
                                                float* __restrict__ out,
                                                const u32* __restrict__ sc,
                                                long long n) {
  const float scale = ((const float*)sc)[2];
  const long long n4 = n >> 2;
  const long long stride = (long long)gridDim.x * 256;
  const float4* x4 = (const float4*)x;
  float4* o4 = (float4*)out;
  for (long long i = (long long)blockIdx.x * 256 + threadIdx.x; i < n4;
       i += stride) {
    float4 v = x4[i];
    float4 o;
    {
      float r = rintf(v.x / scale);
      r = fminf(fmaxf(r, -128.0f), 127.0f);
      float xq = r * scale;
      o.x = v.x + (xq - v.x);
    }
    {
      float r = rintf(v.y / scale);
      r = fminf(fmaxf(r, -128.0f), 127.0f);
      float xq = r * scale;
      o.y = v.y + (xq - v.y);
    }
    {
      float r = rintf(v.z / scale);
      r = fminf(fmaxf(r, -128.0f), 127.0f);
      float xq = r * scale;
      o.z = v.z + (xq - v.z);
    }
    {
      float r = rintf(v.w / scale);
      r = fminf(fmaxf(r, -128.0f), 127.0f);
      float xq = r * scale;
      o.w = v.w + (xq - v.w);
    }
    o4[i] = o;
  }
  for (long long i = (n4 << 2) + (long long)blockIdx.x * 256 + threadIdx.x;
       i < n; i += stride) {
    float v = x[i];
    float r = rintf(v / scale);
    r = fminf(fmaxf(r, -128.0f), 127.0f);
    float xq = r * scale;
    out[i] = v + (xq - v);
  }
}

extern "C" void kernel_launch(void* const* d_in, const int* in_sizes, int n_in,
                              void* d_out, int out_size, void* d_ws,
                              size_t ws_size, hipStream_t stream) {
  const u32* xbits = (const u32*)d_in[0];
  const float* gamma = (const float*)d_in[1];
  const long long n = (long long)in_sizes[0];

  u32* h1 = (u32*)d_ws;        // 2048 u32
  u32* sc = h1 + 2048;         // 8 u32 scalars
  u32* h2 = (u32*)d_out;       // 1M u32 (4 MB) scratch inside output buffer

  const long long k = llround(0.99 * (double)n);

  hipMemsetAsync(d_ws, 0, (2048 + 8) * sizeof(u32), stream);
  hipMemsetAsync(d_out, 0, (size_t)(1u << 20) * sizeof(u32), stream);

  hist_top<<<512, 1024, 0, stream>>>(xbits, h1, n);
  scan_top<<<1, 1024, 0, stream>>>(h1, sc, k);
  hist_low<<<512, 1024, 0, stream>>>(xbits, sc, h2, n);
  scan_low<<<1, 1024, 0, stream>>>(h2, gamma, sc);
  quantize<<<2048, 256, 0, stream>>>((const float*)d_in[0], (float*)d_out, sc,
                                     n);
}

// Round 3
// 287.538 us; speedup vs baseline: 1.4758x; 1.4758x over previous
//
#include <hip/hip_runtime.h>
#include <math.h>

typedef unsigned int u32;
typedef float nfloat4 __attribute__((ext_vector_type(4)));

// ---------------------------------------------------------------------------
// Exact 0.99-quantile of |x| via 2-level radix select on float bit patterns,
// then affine fake-quantize. Selection is bit-exact vs np.sort.
// ws layout (u32): [0..2047] level-1 hist; [2048..2055] scalars
//   sc[0]=top-11-bit bin B1, sc[1]=residual rank, sc[2]=scale bits
//   [2056..3079] chunk sums (1024)
// Level-2 histogram (1M u32 = 4 MB) lives in d_out (overwritten afterwards).
// ---------------------------------------------------------------------------

__global__ __launch_bounds__(1024) void hist_top(const u32* __restrict__ x,
                                                 u32* __restrict__ g1,
                                                 long long n) {
  // 8 interleaved replicas: bin*8 + (tid&7). 64 KB LDS -> 2 blocks/CU.
  __shared__ u32 h[2048 * 8];
  const int t = threadIdx.x;
  for (int i = t; i < 2048 * 8; i += 1024) h[i] = 0;
  __syncthreads();

  const u32 r = (u32)(t & 7);
  const long long n4 = n >> 2;
  const long long stride = (long long)gridDim.x * 1024;
  const uint4* x4 = (const uint4*)x;
  for (long long i = (long long)blockIdx.x * 1024 + t; i < n4; i += stride) {
    uint4 v = x4[i];
    atomicAdd(&h[(((v.x & 0x7fffffffu) >> 20) << 3) + r], 1u);
    atomicAdd(&h[(((v.y & 0x7fffffffu) >> 20) << 3) + r], 1u);
    atomicAdd(&h[(((v.z & 0x7fffffffu) >> 20) << 3) + r], 1u);
    atomicAdd(&h[(((v.w & 0x7fffffffu) >> 20) << 3) + r], 1u);
  }
  for (long long i = (n4 << 2) + (long long)blockIdx.x * 1024 + t; i < n;
       i += stride) {
    atomicAdd(&h[(((x[i] & 0x7fffffffu) >> 20) << 3) + r], 1u);
  }
  __syncthreads();
  for (int i = t; i < 2048; i += 1024) {
    u32 c = 0;
#pragma unroll
    for (int j = 0; j < 8; ++j) c += h[(i << 3) + j];
    if (c) atomicAdd(&g1[i], c);
  }
}

__global__ __launch_bounds__(1024) void scan_top(const u32* __restrict__ g1,
                                                 u32* __restrict__ sc,
                                                 long long k_in) {
  __shared__ u32 s[1024];
  const int t = threadIdx.x;
  uint2 c2 = ((const uint2*)g1)[t];
  const u32 sum = c2.x + c2.y;
  s[t] = sum;
  __syncthreads();
  for (int off = 1; off < 1024; off <<= 1) {
    u32 add = (t >= off) ? s[t - off] : 0u;
    __syncthreads();
    s[t] += add;
    __syncthreads();
  }
  u32 ex = s[t] - sum;
  const u32 k = (u32)k_in;
  u32 cnt[2] = {c2.x, c2.y};
  for (int i = 0; i < 2; ++i) {
    if (k >= ex && k < ex + cnt[i]) {
      sc[0] = (u32)(t * 2 + i);
      sc[1] = k - ex;
    }
    ex += cnt[i];
  }
}

__global__ __launch_bounds__(1024) void hist_low(const u32* __restrict__ x,
                                                 const u32* __restrict__ sc,
                                                 u32* __restrict__ g2,
                                                 long long n) {
  const u32 B1 = sc[0];
  const int t = threadIdx.x;
  const long long n4 = n >> 2;
  const long long stride = (long long)gridDim.x * 1024;
  const uint4* x4 = (const uint4*)x;
  for (long long i = (long long)blockIdx.x * 1024 + t; i < n4; i += stride) {
    uint4 v = x4[i];
    u32 a;
    a = v.x & 0x7fffffffu; if ((a >> 20) == B1) atomicAdd(&g2[a & 0xFFFFFu], 1u);
    a = v.y & 0x7fffffffu; if ((a >> 20) == B1) atomicAdd(&g2[a & 0xFFFFFu], 1u);
    a = v.z & 0x7fffffffu; if ((a >> 20) == B1) atomicAdd(&g2[a & 0xFFFFFu], 1u);
    a = v.w & 0x7fffffffu; if ((a >> 20) == B1) atomicAdd(&g2[a & 0xFFFFFu], 1u);
  }
  for (long long i = (n4 << 2) + (long long)blockIdx.x * 1024 + t; i < n;
       i += stride) {
    u32 a = x[i] & 0x7fffffffu;
    if ((a >> 20) == B1) atomicAdd(&g2[a & 0xFFFFFu], 1u);
  }
}

// 1024 blocks: block b sums level-2 bins [b*1024, b*1024+1024) -> cs[b]
__global__ __launch_bounds__(256) void chunk_reduce(const u32* __restrict__ g2,
                                                    u32* __restrict__ cs) {
  const int t = threadIdx.x;
  uint4 v = ((const uint4*)(g2 + (size_t)blockIdx.x * 1024))[t];
  u32 sum = v.x + v.y + v.z + v.w;
#pragma unroll
  for (int off = 32; off > 0; off >>= 1) sum += __shfl_down(sum, off, 64);
  __shared__ u32 w[4];
  if ((t & 63) == 0) w[t >> 6] = sum;
  __syncthreads();
  if (t == 0) cs[blockIdx.x] = w[0] + w[1] + w[2] + w[3];
}

__global__ __launch_bounds__(1024) void scan_low_final(
    const u32* __restrict__ g2, const u32* __restrict__ cs,
    const float* __restrict__ gamma, u32* __restrict__ sc) {
  __shared__ u32 s[1024];
  __shared__ u32 sChunk, sK2;
  const int t = threadIdx.x;
  const u32 B1 = sc[0];
  const u32 krem = sc[1];

  // Phase A: scan the 1024 chunk sums, pick the chunk containing krem
  const u32 sum = cs[t];
  s[t] = sum;
  __syncthreads();
  for (int off = 1; off < 1024; off <<= 1) {
    u32 add = (t >= off) ? s[t - off] : 0u;
    __syncthreads();
    s[t] += add;
    __syncthreads();
  }
  u32 ex = s[t] - sum;
  if (krem >= ex && krem < ex + sum) {
    sChunk = (u32)t;
    sK2 = krem - ex;
  }
  __syncthreads();
  const u32 c = sChunk;
  const u32 k2 = sK2;

  // Phase B: scan the 1024 bins of the selected chunk (coalesced)
  const u32 cnt = g2[(size_t)c * 1024 + t];
  __syncthreads();
  s[t] = cnt;
  __syncthreads();
  for (int off = 1; off < 1024; off <<= 1) {
    u32 add = (t >= off) ? s[t - off] : 0u;
    __syncthreads();
    s[t] += add;
    __syncthreads();
  }
  ex = s[t] - cnt;
  if (k2 >= ex && k2 < ex + cnt) {
    const u32 bits = (B1 << 20) | (c * 1024u + (u32)t);
    const float q = __uint_as_float(bits);
    float g = gamma[0];
    g = fminf(fmaxf(g, 0.1f), 10.0f);
    const float scale = (q / 127.0f) * g;
    ((float*)sc)[2] = scale;
  }
}

__global__ __launch_bounds__(256) void quantize(const float* __restrict__ x,
                                                float* __restrict__ out,
                                                const u32* __restrict__ sc,
                                                long long n) {
  const float scale = ((const float*)sc)[2];
  const long long n4 = n >> 2;
  const long long stride = (long long)gridDim.x * 256;
  const float4* x4 = (const float4*)x;
  nfloat4* o4 = (nfloat4*)out;
  for (long long i = (long long)blockIdx.x * 256 + threadIdx.x; i < n4;
       i += stride) {
    float4 v = x4[i];
    nfloat4 o;
    {
      float r = rintf(v.x / scale);
      r = fminf(fmaxf(r, -128.0f), 127.0f);
      o.x = r * scale;
    }
    {
      float r = rintf(v.y / scale);
      r = fminf(fmaxf(r, -128.0f), 127.0f);
      o.y = r * scale;
    }
    {
      float r = rintf(v.z / scale);
      r = fminf(fmaxf(r, -128.0f), 127.0f);
      o.z = r * scale;
    }
    {
      float r = rintf(v.w / scale);
      r = fminf(fmaxf(r, -128.0f), 127.0f);
      o.w = r * scale;
    }
    __builtin_nontemporal_store(o, &o4[i]);
  }
  for (long long i = (n4 << 2) + (long long)blockIdx.x * 256 + threadIdx.x;
       i < n; i += stride) {
    float v = x[i];
    float r = rintf(v / scale);
    r = fminf(fmaxf(r, -128.0f), 127.0f);
    out[i] = r * scale;
  }
}

extern "C" void kernel_launch(void* const* d_in, const int* in_sizes, int n_in,
                              void* d_out, int out_size, void* d_ws,
                              size_t ws_size, hipStream_t stream) {
  const u32* xbits = (const u32*)d_in[0];
  const float* gamma = (const float*)d_in[1];
  const long long n = (long long)in_sizes[0];

  u32* h1 = (u32*)d_ws;   // 2048 u32
  u32* sc = h1 + 2048;    // 8 u32 scalars
  u32* cs = sc + 8;       // 1024 u32 chunk sums
  u32* h2 = (u32*)d_out;  // 1M u32 (4 MB) scratch inside output buffer

  const long long k = llround(0.99 * (double)n);

  (void)hipMemsetAsync(d_ws, 0, (2048 + 8) * sizeof(u32), stream);
  (void)hipMemsetAsync(d_out, 0, (size_t)(1u << 20) * sizeof(u32), stream);

  hist_top<<<512, 1024, 0, stream>>>(xbits, h1, n);
  scan_top<<<1, 1024, 0, stream>>>(h1, sc, k);
  hist_low<<<512, 1024, 0, stream>>>(xbits, sc, h2, n);
  chunk_reduce<<<1024, 256, 0, stream>>>(h2, cs);
  scan_low_final<<<1, 1024, 0, stream>>>(h2, cs, gamma, sc);
  quantize<<<2048, 256, 0, stream>>>((const float*)d_in[0], (float*)d_out, sc,
                                     n);
}